// Round 1
// baseline (4163.464 us; speedup 1.0000x reference)
//
#include <hip/hip_runtime.h>
#include <math.h>

#define B_  32
#define C_  64
#define T_  12
#define NV  883
#define TTW 10          // T-2 output time steps
#define K3  2649        // 3*NV
#define NG  3

// Fused STSGCL kernel.
// Stage 1: g[c, m] = sum_k hc[b,c,t,k] * adj[NV+m, k]   (64x64 tile, K=2649)
//   hc[b,c,t,k] = x[b,c,t+k/NV, k%NV] + temb[c, t+k/NV] + semb[c, k%NV]
// Stage 2 (fused epilogue): z[gi,p,d] = sum_c g[c,p] * W[gi,c,d] + bias[gi,d]
//   out[p,c] = max_gi z[gi,p,c] * sigmoid(z[gi,p,c+64]); write transposed+sliced.
__global__ __launch_bounds__(256) void stsgcl_fused(
    const float* __restrict__ x,
    const float* __restrict__ temb,
    const float* __restrict__ semb,
    const float* __restrict__ adj,
    const float* __restrict__ Wg,
    const float* __restrict__ bias,
    float* __restrict__ out)
{
    __shared__ union {
        struct { float As[32][64]; float Bs[32][64]; } s1;  // 16 KB
        float Ws[64][128];                                  // 32 KB
    } sm;
    __shared__ float Gs[64][64];                            // 16 KB

    const int tid = threadIdx.x;
    const int bt  = blockIdx.y;          // b*10 + t
    const int bb  = bt / TTW;
    const int t   = bt % TTW;
    const int m0  = blockIdx.x * 64;

    // stage-1 compute mapping: rows (c) = 4*tr.., cols (m) = 4*tc..
    const int tr = tid >> 4;             // 0..15
    const int tc = tid & 15;             // 0..15

    // loader mapping: each thread loads 8 consecutive k of one row
    const int lrow = tid >> 2;           // 0..63 (c for A, m for B)
    const int kq   = (tid & 3) * 8;      // 0,8,16,24

    const float* xrow = x   + ((size_t)(bb * C_ + lrow) * T_ + t) * NV;
    const float* brow = adj + (size_t)(NV + m0 + lrow) * K3;   // rows 883..1778, always in-bounds
    const float* srow = semb + (size_t)lrow * NV;
    const float  te0 = temb[lrow * T_ + t];
    const float  te1 = temb[lrow * T_ + t + 1];
    const float  te2 = temb[lrow * T_ + t + 2];

    float acc[4][4];
#pragma unroll
    for (int i = 0; i < 4; ++i)
#pragma unroll
        for (int j = 0; j < 4; ++j) acc[i][j] = 0.f;

    const int KTILES = (K3 + 31) / 32;   // 83 (last tile 25 wide, zero-padded on A side)
    for (int kt = 0; kt < KTILES; ++kt) {
        const int kg0 = kt * 32 + kq;
        // ---- A tile (embedding-add fused); zero-pad k >= K3 ----
        {
            int tt, n;
            if (kg0 >= 2 * NV)      { tt = 2; n = kg0 - 2 * NV; }
            else if (kg0 >= NV)     { tt = 1; n = kg0 - NV; }
            else                    { tt = 0; n = kg0; }
#pragma unroll
            for (int i = 0; i < 8; ++i) {
                float v = 0.f;
                if (kg0 + i < K3) {
                    const float tev = (tt == 0) ? te0 : ((tt == 1) ? te1 : te2);
                    v = xrow[tt * NV + n] + tev + srow[n];
                }
                sm.s1.As[kq + i][lrow] = v;
                if (++n == NV) { n = 0; ++tt; }
            }
        }
        // ---- B tile: adj middle rows; k-overrun reads stay in-bounds, masked by As zeros ----
#pragma unroll
        for (int i = 0; i < 8; ++i) {
            sm.s1.Bs[kq + i][lrow] = brow[kg0 + i];
        }
        __syncthreads();
#pragma unroll
        for (int kk = 0; kk < 32; ++kk) {
            const float4 a  = *(const float4*)&sm.s1.As[kk][tr * 4];
            const float4 bv = *(const float4*)&sm.s1.Bs[kk][tc * 4];
            const float av[4] = {a.x, a.y, a.z, a.w};
            const float bw[4] = {bv.x, bv.y, bv.z, bv.w};
#pragma unroll
            for (int i = 0; i < 4; ++i)
#pragma unroll
                for (int j = 0; j < 4; ++j) acc[i][j] += av[i] * bw[j];
        }
        __syncthreads();
    }

    // ---- stash g tile to LDS as Gs[c][m] ----
#pragma unroll
    for (int i = 0; i < 4; ++i)
#pragma unroll
        for (int j = 0; j < 4; ++j) Gs[tr * 4 + i][tc * 4 + j] = acc[i][j];

    // ---- stage 2: per-branch channel linear + GLU, max over branches ----
    const int pg = tid & 15;   // pos group (m): 4 positions
    const int cg = tid >> 4;   // out-channel group: 4 channels

    float omax[4][4];
#pragma unroll
    for (int i = 0; i < 4; ++i)
#pragma unroll
        for (int j = 0; j < 4; ++j) omax[i][j] = -3.4e38f;

    for (int gi = 0; gi < NG; ++gi) {
        __syncthreads();   // Gs visible (gi=0) / previous Ws reads done (gi>0)
        {
            const float4* wsrc = (const float4*)(Wg + (size_t)gi * C_ * 128);
            float4* wdst = (float4*)&sm.Ws[0][0];
#pragma unroll
            for (int i = 0; i < 8; ++i) wdst[tid + i * 256] = wsrc[tid + i * 256];
        }
        __syncthreads();

        float z1[4][4], z2[4][4];
#pragma unroll
        for (int j = 0; j < 4; ++j) {
            const float b1 = bias[gi * 128 + cg * 4 + j];
            const float b2 = bias[gi * 128 + 64 + cg * 4 + j];
#pragma unroll
            for (int i = 0; i < 4; ++i) { z1[i][j] = b1; z2[i][j] = b2; }
        }
#pragma unroll 8
        for (int cc = 0; cc < 64; ++cc) {
            const float4 gv = *(const float4*)&Gs[cc][pg * 4];
            const float4 w1 = *(const float4*)&sm.Ws[cc][cg * 4];
            const float4 w2 = *(const float4*)&sm.Ws[cc][64 + cg * 4];
            const float gva[4] = {gv.x, gv.y, gv.z, gv.w};
            const float w1a[4] = {w1.x, w1.y, w1.z, w1.w};
            const float w2a[4] = {w2.x, w2.y, w2.z, w2.w};
#pragma unroll
            for (int i = 0; i < 4; ++i)
#pragma unroll
                for (int j = 0; j < 4; ++j) {
                    z1[i][j] += gva[i] * w1a[j];
                    z2[i][j] += gva[i] * w2a[j];
                }
        }
#pragma unroll
        for (int i = 0; i < 4; ++i)
#pragma unroll
            for (int j = 0; j < 4; ++j) {
                const float s = 1.0f / (1.0f + __expf(-z2[i][j]));
                const float v = z1[i][j] * s;
                omax[i][j] = fmaxf(omax[i][j], v);
            }
    }

    // ---- write out[b, c, t, m] (slice already applied via adj-row offset) ----
    const int mmb = m0 + pg * 4;
#pragma unroll
    for (int j = 0; j < 4; ++j) {
        const int co = cg * 4 + j;
        float* orow = out + ((size_t)(bb * C_ + co) * TTW + t) * NV;
#pragma unroll
        for (int i = 0; i < 4; ++i) {
            const int mm = mmb + i;
            if (mm < NV) orow[mm] = omax[i][j];
        }
    }
}

extern "C" void kernel_launch(void* const* d_in, const int* in_sizes, int n_in,
                              void* d_out, int out_size, void* d_ws, size_t ws_size,
                              hipStream_t stream) {
    (void)in_sizes; (void)n_in; (void)d_ws; (void)ws_size; (void)out_size;
    const float* x    = (const float*)d_in[0];
    const float* temb = (const float*)d_in[1];
    const float* semb = (const float*)d_in[2];
    const float* adj  = (const float*)d_in[3];
    const float* Wg   = (const float*)d_in[4];
    const float* bias = (const float*)d_in[5];
    float* out = (float*)d_out;

    dim3 grid((NV + 63) / 64, B_ * TTW);   // (14, 320)
    stsgcl_fused<<<grid, 256, 0, stream>>>(x, temb, semb, adj, Wg, bias, out);
}

// Round 2
// 695.760 us; speedup vs baseline: 5.9840x; 5.9840x over previous
//
#include <hip/hip_runtime.h>
#include <math.h>

#define B_   32
#define C_   64
#define T_   12
#define NV   883
#define TTW  10          // T-2 output time steps
#define K3   2649        // 3*NV
#define KT_N 83          // ceil(K3/32)
#define MT_N 14          // ceil(NV/64)

typedef __attribute__((ext_vector_type(8))) short bf16x8;   // 8 bf16 = 4 VGPRs (MFMA A/B frag)
typedef __attribute__((ext_vector_type(4))) float f32x4;    // MFMA C/D frag
typedef __attribute__((ext_vector_type(4))) unsigned int u32x4;

// ---- workspace layout ----
#define WS_B_OFF   0u
#define WS_B_BYTES (14u*83u*4u*64u*16u)            // 4,759,552  bf16 B-fragments of adj middle rows
#define WS_W_OFF   (WS_B_OFF + WS_B_BYTES)
#define WS_W_BYTES (48u*64u*16u)                   // 49,152     bf16 B2-fragments of W
#define WS_H_OFF   (WS_W_OFF + WS_W_BYTES)         // 4,808,704 (16B aligned)
#define H_ELEMS    ((size_t)B_ * C_ * T_ * NV)     // 21,700,608
#define WS_NEED    (WS_H_OFF + H_ELEMS * 4u)       // ~91.6 MB

__device__ __forceinline__ unsigned short f2bf(float f) {
    union { float f; unsigned int u; } v; v.f = f;
    unsigned int r = v.u + 0x7fffu + ((v.u >> 16) & 1u);   // RNE
    return (unsigned short)(r >> 16);
}

// ---------------- prep kernels (re-run every launch; ws is re-poisoned) ----------------

// h[b,c,t,n] = x + temb[c,t] + semb[c,n]   (fp32, contiguous — hc window = slice at t*883)
__global__ __launch_bounds__(256) void prep_h(const float* __restrict__ x,
                                              const float* __restrict__ temb,
                                              const float* __restrict__ semb,
                                              float* __restrict__ h) {
    size_t i = (size_t)blockIdx.x * 256 + threadIdx.x;   // grid sized exactly
    int n = (int)(i % NV);
    int r = (int)(i / NV);
    int t = r % T_;
    int c = (r / T_) & (C_ - 1);
    h[i] = x[i] + temb[c * T_ + t] + semb[c * NV + n];
}

// Bprep: chunk = (mt*83 + kt)*4 + w ; lane l holds adj[NV + mt*64 + 16w + (l&15)][kt*32 + (l>>4)*8 + j]
__global__ __launch_bounds__(256) void prep_b(const float* __restrict__ adj,
                                              u32x4* __restrict__ bp) {
    const int chunk = blockIdx.x * 4 + (threadIdx.x >> 6);   // 0..4647
    const int l = threadIdx.x & 63;
    const int mt = chunk / 332;
    const int rem = chunk - mt * 332;
    const int kt = rem >> 2;
    const int w  = rem & 3;
    const int row = NV + mt * 64 + 16 * w + (l & 15);        // ≤1778 < 2649, always valid
    const int k0  = kt * 32 + (l >> 4) * 8;
    const float* src = adj + (size_t)row * K3;
    unsigned short u[8];
#pragma unroll
    for (int i = 0; i < 8; ++i) {
        int k = k0 + i;
        u[i] = (k < K3) ? f2bf(src[k]) : (unsigned short)0;
    }
    u32x4 pk;
    pk[0] = u[0] | ((unsigned)u[1] << 16);
    pk[1] = u[2] | ((unsigned)u[3] << 16);
    pk[2] = u[4] | ((unsigned)u[5] << 16);
    pk[3] = u[6] | ((unsigned)u[7] << 16);
    bp[(size_t)chunk * 64 + l] = pk;
}

// Wpack: chunk = (gi*8+df)*2 + kc ; lane l holds W[gi][kc*32 + (l>>4)*8 + j][16*df + (l&15)]
__global__ __launch_bounds__(256) void prep_w(const float* __restrict__ W,
                                              u32x4* __restrict__ wp) {
    const int chunk = blockIdx.x * 4 + (threadIdx.x >> 6);   // 0..47
    const int l = threadIdx.x & 63;
    const int c24 = chunk >> 1;     // gi*8 + df
    const int kc  = chunk & 1;
    const int gi  = c24 >> 3;
    const int df  = c24 & 7;
    const int d   = 16 * df + (l & 15);
    const int c0  = kc * 32 + (l >> 4) * 8;
    const float* src = W + (size_t)gi * C_ * 128 + d;
    unsigned short u[8];
#pragma unroll
    for (int i = 0; i < 8; ++i) u[i] = f2bf(src[(size_t)(c0 + i) * 128]);
    u32x4 pk;
    pk[0] = u[0] | ((unsigned)u[1] << 16);
    pk[1] = u[2] | ((unsigned)u[3] << 16);
    pk[2] = u[4] | ((unsigned)u[5] << 16);
    pk[3] = u[6] | ((unsigned)u[7] << 16);
    wp[(size_t)chunk * 64 + l] = pk;
}

// ---------------- main fused kernel (bf16 MFMA both stages) ----------------
__global__ __launch_bounds__(256) void stsgcl_mfma(
    const float* __restrict__ h,
    const bf16x8* __restrict__ Bp,
    const bf16x8* __restrict__ Wp,
    const float* __restrict__ bias,
    float* __restrict__ out)
{
    __shared__ short As[4 * 64 * 8];      // 4 KB: A-tile in fragment-packed order
    __shared__ short Gs[4 * 2 * 64 * 8];  // 8 KB: g quad-shuffle buffer (A2 frag order)

    const int tid  = threadIdx.x;
    const int lane = tid & 63;
    const int w    = tid >> 6;            // wave id: n-strip (stage1) / m-strip owner (stage2)
    const int q    = lane >> 4;
    const int lo   = lane & 15;
    const int mt   = blockIdx.x;
    const int bt   = blockIdx.y;
    const int bb   = bt / TTW;
    const int t    = bt - bb * TTW;

    // ---- staging mapping: thread loads 8 consecutive k of channel sc ----
    const int sc = tid >> 2;              // 0..63
    const int sq = tid & 3;               // k-quad of 8 within 32
    const float* hrow = h + (size_t)(bb * C_ + sc) * (T_ * NV) + t * NV;  // contiguous 2649 window
    u32x4* aslot = (u32x4*)As + ((sc >> 4) * 64 + ((sc & 15) | (sq << 4)));

    const bf16x8* bptr = Bp + ((size_t)(mt * KT_N) * 4 + w) * 64 + lane;

    f32x4 acc1[4];
#pragma unroll
    for (int mf = 0; mf < 4; ++mf)
#pragma unroll
        for (int r = 0; r < 4; ++r) acc1[mf][r] = 0.f;

    for (int kt = 0; kt < KT_N; ++kt) {
        const int k0 = kt * 32 + sq * 8;
        float v[8];
        if (kt < KT_N - 1) {
#pragma unroll
            for (int i = 0; i < 8; ++i) v[i] = hrow[k0 + i];
        } else {
#pragma unroll
            for (int i = 0; i < 8; ++i) v[i] = (k0 + i < K3) ? hrow[k0 + i] : 0.f;
        }
        u32x4 pk;
        pk[0] = f2bf(v[0]) | ((unsigned)f2bf(v[1]) << 16);
        pk[1] = f2bf(v[2]) | ((unsigned)f2bf(v[3]) << 16);
        pk[2] = f2bf(v[4]) | ((unsigned)f2bf(v[5]) << 16);
        pk[3] = f2bf(v[6]) | ((unsigned)f2bf(v[7]) << 16);
        bf16x8 bfrag = *bptr;  bptr += 256;     // own n-strip B frag (global, bf16-prepped)
        *aslot = pk;                            // ds_write_b128, wave-contiguous
        __syncthreads();
        bf16x8 af0 = ((const bf16x8*)As)[0 * 64 + lane];
        bf16x8 af1 = ((const bf16x8*)As)[1 * 64 + lane];
        bf16x8 af2 = ((const bf16x8*)As)[2 * 64 + lane];
        bf16x8 af3 = ((const bf16x8*)As)[3 * 64 + lane];
        acc1[0] = __builtin_amdgcn_mfma_f32_16x16x32_bf16(af0, bfrag, acc1[0], 0, 0, 0);
        acc1[1] = __builtin_amdgcn_mfma_f32_16x16x32_bf16(af1, bfrag, acc1[1], 0, 0, 0);
        acc1[2] = __builtin_amdgcn_mfma_f32_16x16x32_bf16(af2, bfrag, acc1[2], 0, 0, 0);
        acc1[3] = __builtin_amdgcn_mfma_f32_16x16x32_bf16(af3, bfrag, acc1[3], 0, 0, 0);
        __syncthreads();
    }

    // ---- quad-shuffle g (C/D layout) -> A2 operand layout, intra-wave via LDS ----
    // lane holds g[c = 16mf + 4q + r][m = 16w + lo]; A2 slot: [(w*2+kc)*64 + ((m&15)|(hi2<<4))]*8 + j
#pragma unroll
    for (int mf = 0; mf < 4; ++mf) {
        unsigned int p0 = f2bf(acc1[mf][0]) | ((unsigned)f2bf(acc1[mf][1]) << 16);
        unsigned int p1 = f2bf(acc1[mf][2]) | ((unsigned)f2bf(acc1[mf][3]) << 16);
        const int kc  = mf >> 1;
        const int hi2 = ((mf & 1) << 1) | (q >> 1);
        const int j0  = (q & 1) * 4;
        unsigned int* dst = (unsigned int*)(Gs + (((w * 2 + kc) * 64) + (lo | (hi2 << 4))) * 8 + j0);
        dst[0] = p0;
        dst[1] = p1;
    }
    // wave reads only its own region (mf2 = w): same-wave RAW, compiler orders via lgkmcnt.

    // ---- stage 2: z[gi, m, d] = g^T . W[gi] ; all 3 branches per wave (m-strip = 16w..16w+15) ----
    f32x4 acc2[24];
#pragma unroll
    for (int i = 0; i < 24; ++i)
#pragma unroll
        for (int r = 0; r < 4; ++r) acc2[i][r] = 0.f;

#pragma unroll
    for (int kc = 0; kc < 2; ++kc) {
        bf16x8 a2 = ((const bf16x8*)Gs)[(w * 2 + kc) * 64 + lane];
#pragma unroll
        for (int c24 = 0; c24 < 24; ++c24) {
            bf16x8 wf = Wp[(c24 * 2 + kc) * 64 + lane];
            acc2[c24] = __builtin_amdgcn_mfma_f32_16x16x32_bf16(a2, wf, acc2[c24], 0, 0, 0);
        }
    }

    // ---- GLU + max over branches + transposed sliced store ----
    const int mbase = mt * 64 + 16 * w + 4 * q;
#pragma unroll
    for (int f = 0; f < 4; ++f) {
        float om[4] = {-3.4e38f, -3.4e38f, -3.4e38f, -3.4e38f};
#pragma unroll
        for (int gi = 0; gi < 3; ++gi) {
            const float b1 = bias[gi * 128 + 16 * f + lo];
            const float b2 = bias[gi * 128 + 64 + 16 * f + lo];
#pragma unroll
            for (int r = 0; r < 4; ++r) {
                const float z1 = acc2[gi * 8 + f][r] + b1;
                const float z2 = acc2[gi * 8 + 4 + f][r] + b2;
                const float sg = 1.0f / (1.0f + __expf(-z2));
                om[r] = fmaxf(om[r], z1 * sg);
            }
        }
        const int cout = 16 * f + lo;
        float* orow = out + ((size_t)(bb * C_ + cout) * TTW + t) * NV;
#pragma unroll
        for (int r = 0; r < 4; ++r) {
            const int mv = mbase + r;
            if (mv < NV) orow[mv] = om[r];
        }
    }
}

// ---------------- fallback: round-1 verified fp32 kernel (used if ws too small) ----------------
__global__ __launch_bounds__(256) void stsgcl_fused(
    const float* __restrict__ x, const float* __restrict__ temb,
    const float* __restrict__ semb, const float* __restrict__ adj,
    const float* __restrict__ Wg, const float* __restrict__ bias,
    float* __restrict__ out)
{
    __shared__ union {
        struct { float As[32][64]; float Bs[32][64]; } s1;
        float Ws[64][128];
    } sm;
    __shared__ float Gsf[64][64];

    const int tid = threadIdx.x;
    const int bt = blockIdx.y;
    const int bb = bt / TTW;
    const int t  = bt % TTW;
    const int m0 = blockIdx.x * 64;
    const int tr = tid >> 4, tc = tid & 15;
    const int lrow = tid >> 2;
    const int kq = (tid & 3) * 8;

    const float* xrow = x + ((size_t)(bb * C_ + lrow) * T_ + t) * NV;
    const float* brow = adj + (size_t)(NV + m0 + lrow) * K3;
    const float* srow = semb + (size_t)lrow * NV;
    const float te0 = temb[lrow * T_ + t], te1 = temb[lrow * T_ + t + 1], te2 = temb[lrow * T_ + t + 2];

    float acc[4][4];
#pragma unroll
    for (int i = 0; i < 4; ++i)
#pragma unroll
        for (int j = 0; j < 4; ++j) acc[i][j] = 0.f;

    for (int kt = 0; kt < (K3 + 31) / 32; ++kt) {
        const int kg0 = kt * 32 + kq;
        {
            int tt, n;
            if (kg0 >= 2 * NV) { tt = 2; n = kg0 - 2 * NV; }
            else if (kg0 >= NV) { tt = 1; n = kg0 - NV; }
            else { tt = 0; n = kg0; }
#pragma unroll
            for (int i = 0; i < 8; ++i) {
                float v = 0.f;
                if (kg0 + i < K3) {
                    const float tev = (tt == 0) ? te0 : ((tt == 1) ? te1 : te2);
                    v = xrow[tt * NV + n] + tev + srow[n];
                }
                sm.s1.As[kq + i][lrow] = v;
                if (++n == NV) { n = 0; ++tt; }
            }
        }
#pragma unroll
        for (int i = 0; i < 8; ++i) sm.s1.Bs[kq + i][lrow] = brow[kg0 + i];
        __syncthreads();
#pragma unroll
        for (int kk = 0; kk < 32; ++kk) {
            const float4 a = *(const float4*)&sm.s1.As[kk][tr * 4];
            const float4 bv = *(const float4*)&sm.s1.Bs[kk][tc * 4];
            const float av[4] = {a.x, a.y, a.z, a.w};
            const float bw[4] = {bv.x, bv.y, bv.z, bv.w};
#pragma unroll
            for (int i = 0; i < 4; ++i)
#pragma unroll
                for (int j = 0; j < 4; ++j) acc[i][j] += av[i] * bw[j];
        }
        __syncthreads();
    }
#pragma unroll
    for (int i = 0; i < 4; ++i)
#pragma unroll
        for (int j = 0; j < 4; ++j) Gsf[tr * 4 + i][tc * 4 + j] = acc[i][j];

    const int pg = tid & 15, cg = tid >> 4;
    float omax[4][4];
#pragma unroll
    for (int i = 0; i < 4; ++i)
#pragma unroll
        for (int j = 0; j < 4; ++j) omax[i][j] = -3.4e38f;

    for (int gi = 0; gi < 3; ++gi) {
        __syncthreads();
        {
            const float4* wsrc = (const float4*)(Wg + (size_t)gi * C_ * 128);
            float4* wdst = (float4*)&sm.Ws[0][0];
#pragma unroll
            for (int i = 0; i < 8; ++i) wdst[tid + i * 256] = wsrc[tid + i * 256];
        }
        __syncthreads();
        float z1[4][4], z2[4][4];
#pragma unroll
        for (int j = 0; j < 4; ++j) {
            const float b1 = bias[gi * 128 + cg * 4 + j];
            const float b2 = bias[gi * 128 + 64 + cg * 4 + j];
#pragma unroll
            for (int i = 0; i < 4; ++i) { z1[i][j] = b1; z2[i][j] = b2; }
        }
#pragma unroll 8
        for (int cc = 0; cc < 64; ++cc) {
            const float4 gv = *(const float4*)&Gsf[cc][pg * 4];
            const float4 w1 = *(const float4*)&sm.Ws[cc][cg * 4];
            const float4 w2 = *(const float4*)&sm.Ws[cc][64 + cg * 4];
            const float gva[4] = {gv.x, gv.y, gv.z, gv.w};
            const float w1a[4] = {w1.x, w1.y, w1.z, w1.w};
            const float w2a[4] = {w2.x, w2.y, w2.z, w2.w};
#pragma unroll
            for (int i = 0; i < 4; ++i)
#pragma unroll
                for (int j = 0; j < 4; ++j) { z1[i][j] += gva[i] * w1a[j]; z2[i][j] += gva[i] * w2a[j]; }
        }
#pragma unroll
        for (int i = 0; i < 4; ++i)
#pragma unroll
            for (int j = 0; j < 4; ++j) {
                const float s = 1.0f / (1.0f + __expf(-z2[i][j]));
                omax[i][j] = fmaxf(omax[i][j], z1[i][j] * s);
            }
    }
    const int mmb = m0 + pg * 4;
#pragma unroll
    for (int j = 0; j < 4; ++j) {
        const int co = cg * 4 + j;
        float* orow = out + ((size_t)(bb * C_ + co) * TTW + t) * NV;
#pragma unroll
        for (int i = 0; i < 4; ++i) {
            const int mm = mmb + i;
            if (mm < NV) orow[mm] = omax[i][j];
        }
    }
}

extern "C" void kernel_launch(void* const* d_in, const int* in_sizes, int n_in,
                              void* d_out, int out_size, void* d_ws, size_t ws_size,
                              hipStream_t stream) {
    (void)in_sizes; (void)n_in; (void)out_size;
    const float* x    = (const float*)d_in[0];
    const float* temb = (const float*)d_in[1];
    const float* semb = (const float*)d_in[2];
    const float* adj  = (const float*)d_in[3];
    const float* Wg   = (const float*)d_in[4];
    const float* bias = (const float*)d_in[5];
    float* out = (float*)d_out;

    if (ws_size >= (size_t)WS_NEED) {
        float*  h  = (float*)((char*)d_ws + WS_H_OFF);
        u32x4*  bp = (u32x4*)((char*)d_ws + WS_B_OFF);
        u32x4*  wp = (u32x4*)((char*)d_ws + WS_W_OFF);

        prep_h<<<dim3((unsigned)(H_ELEMS / 256)), 256, 0, stream>>>(x, temb, semb, h);
        prep_b<<<dim3(1162), 256, 0, stream>>>(adj, bp);
        prep_w<<<dim3(12), 256, 0, stream>>>(Wg, wp);

        dim3 grid(MT_N, B_ * TTW);   // (14, 320)
        stsgcl_mfma<<<grid, 256, 0, stream>>>(h, (const bf16x8*)bp, (const bf16x8*)wp, bias, out);
    } else {
        dim3 grid(MT_N, B_ * TTW);
        stsgcl_fused<<<grid, 256, 0, stream>>>(x, temb, semb, adj, Wg, bias, out);
    }
}

// Round 3
// 571.093 us; speedup vs baseline: 7.2903x; 1.2183x over previous
//
#include <hip/hip_runtime.h>
#include <math.h>

#define B_   32
#define C_   64
#define T_   12
#define NV   883
#define TTW  10          // T-2 output time steps
#define K3   2649        // 3*NV
#define KSEG 28          // k-tiles per 883-segment (28*32=896, zero-padded)

typedef __attribute__((ext_vector_type(8))) short bf16x8;   // 8 bf16 = 4 VGPRs (MFMA A/B frag)
typedef __attribute__((ext_vector_type(4))) float f32x4;    // MFMA C/D frag
typedef __attribute__((ext_vector_type(4))) unsigned int u32x4;

// ---- workspace layout (all 16B aligned) ----
// Apk: [b*12+s][kt<28][af<4][lane<64] x 16B  = 384*28*4*1024 = 44,040,192
// Bpk: [bx2<14][seg<3][kt<28][bfi<4][lane]   = 14*3*28*4*1024 = 4,816,896
// Wpk: [(gi*8+df)*2+kc][lane]                = 48*1024 = 49,152
#define WS_A_OFF   0ull
#define WS_A_BYTES 44040192ull
#define WS_B_OFF   (WS_A_OFF + WS_A_BYTES)
#define WS_B_BYTES 4816896ull
#define WS_W_OFF   (WS_B_OFF + WS_B_BYTES)
#define WS_W_BYTES 49152ull
#define WS_NEED    (WS_W_OFF + WS_W_BYTES)   // 48,906,240

__device__ __forceinline__ unsigned short f2bf(float f) {
    union { float f; unsigned int u; } v; v.f = f;
    unsigned int r = v.u + 0x7fffu + ((v.u >> 16) & 1u);   // RNE
    return (unsigned short)(r >> 16);
}

// ---------------- prep kernels ----------------

// A-pack: h = x + temb + semb per (b, s, c-half), bf16, MFMA A-fragment order.
// grid = 384*2 blocks; LDS-staged so global reads+writes are fully coalesced.
__global__ __launch_bounds__(256) void prep_a(const float* __restrict__ x,
                                              const float* __restrict__ temb,
                                              const float* __restrict__ semb,
                                              bf16x8* __restrict__ Apk) {
    __shared__ short hs[32 * 896];          // 57,344 B
    const int tid = threadIdx.x;
    const int bs  = blockIdx.x >> 1;        // 0..383 = b*12 + s
    const int ch  = blockIdx.x & 1;         // channel half
    const int b   = bs / 12, s = bs - b * 12;

    for (int cl = 0; cl < 32; ++cl) {
        const int c = ch * 32 + cl;
        const float te = temb[c * T_ + s];
        const float* xr = x + ((size_t)(b * C_ + c) * T_ + s) * NV;
        const float* sr = semb + (size_t)c * NV;
        for (int k = tid; k < 896; k += 256) {
            float v = (k < NV) ? (xr[k] + te + sr[k]) : 0.f;
            hs[cl * 896 + k] = (short)f2bf(v);
        }
    }
    __syncthreads();
    // frags for this half: kt<28 x a2<2 x lane<64 = 3584
    for (int i = tid; i < 3584; i += 256) {
        const int lane = i & 63;
        const int chunk = i >> 6;           // kt*2 + a2
        const int kt = chunk >> 1, a2 = chunk & 1;
        const int af = ch * 2 + a2;
        const int cl = a2 * 16 + (lane & 15);
        const int k0 = kt * 32 + (lane >> 4) * 8;
        const bf16x8 vv = *(const bf16x8*)&hs[cl * 896 + k0];
        Apk[(size_t)((bs * KSEG + kt) * 4 + af) * 64 + lane] = vv;
    }
}

// B-pack: adj middle rows -> bf16 B-fragments split per time-segment, zero-padded K.
__global__ __launch_bounds__(256) void prep_b(const float* __restrict__ adj,
                                              u32x4* __restrict__ Bpk) {
    const int chunk = blockIdx.x * 4 + (threadIdx.x >> 6);   // 0..4703
    const int l = threadIdx.x & 63;
    const int bfi = chunk & 3;
    int tmp = chunk >> 2;
    const int kt = tmp % KSEG;  tmp /= KSEG;
    const int seg = tmp % 3;
    const int bx2 = tmp / 3;                                  // 0..13
    const int m16 = bx2 * 4 + bfi;                            // 0..55
    const int row = NV + m16 * 16 + (l & 15);                 // <= 1778 < 2649
    const float* src = adj + (size_t)row * K3 + seg * NV;
    const int k0 = kt * 32 + (l >> 4) * 8;
    unsigned short u[8];
#pragma unroll
    for (int i = 0; i < 8; ++i) {
        const int kk = k0 + i;
        u[i] = (kk < NV) ? f2bf(src[kk]) : (unsigned short)0;
    }
    u32x4 pk;
    pk[0] = u[0] | ((unsigned)u[1] << 16);
    pk[1] = u[2] | ((unsigned)u[3] << 16);
    pk[2] = u[4] | ((unsigned)u[5] << 16);
    pk[3] = u[6] | ((unsigned)u[7] << 16);
    Bpk[(size_t)chunk * 64 + l] = pk;
}

// W-pack: [gi][c][2C] -> bf16 B-fragments. chunk = (gi*8+df)*2 + kc.
__global__ __launch_bounds__(256) void prep_w(const float* __restrict__ W,
                                              u32x4* __restrict__ Wpk) {
    const int chunk = blockIdx.x * 4 + (threadIdx.x >> 6);   // 0..47
    const int l = threadIdx.x & 63;
    const int c24 = chunk >> 1;
    const int kc  = chunk & 1;
    const int gi  = c24 >> 3;
    const int df  = c24 & 7;
    const int d   = 16 * df + (l & 15);
    const int c0  = kc * 32 + (l >> 4) * 8;
    const float* src = W + (size_t)gi * C_ * 128 + d;
    unsigned short u[8];
#pragma unroll
    for (int i = 0; i < 8; ++i) u[i] = f2bf(src[(size_t)(c0 + i) * 128]);
    u32x4 pk;
    pk[0] = u[0] | ((unsigned)u[1] << 16);
    pk[1] = u[2] | ((unsigned)u[3] << 16);
    pk[2] = u[4] | ((unsigned)u[5] << 16);
    pk[3] = u[6] | ((unsigned)u[7] << 16);
    Wpk[(size_t)chunk * 64 + l] = pk;
}

// ---------------- main kernel: barrier-free register GEMM + fused GLU epilogue ----------------
// block = 128 m x 2 bt; wave = 64 m x 1 bt; acc1 = 4 af x 4 bf f32x4.
__global__ __launch_bounds__(256) void stsgcl_main(
    const bf16x8* __restrict__ Apk,
    const bf16x8* __restrict__ Bpk,
    const bf16x8* __restrict__ Wpk,
    const float* __restrict__ bias,
    float* __restrict__ out)
{
    __shared__ short Gs[4 * 64 * 72];       // per-wave 64m x 72c (padded) bf16 = 36,864 B

    const int tid  = threadIdx.x;
    const int lane = tid & 63;
    const int w    = tid >> 6;
    const int q    = lane >> 4;
    const int lo   = lane & 15;
    const int btl  = w >> 1;                // bt within pair
    const int mh   = w & 1;                 // 64-m half
    const int bx   = blockIdx.x;            // 0..6
    const int bt   = blockIdx.y * 2 + btl;  // 0..319 (pair shares b: 10 even)
    const int bb   = bt / TTW;
    const int t    = bt - bb * TTW;
    const int bx2  = bx * 2 + mh;           // 0..13

    f32x4 acc[4][4];
#pragma unroll
    for (int i = 0; i < 4; ++i)
#pragma unroll
        for (int j = 0; j < 4; ++j)
#pragma unroll
            for (int r = 0; r < 4; ++r) acc[i][j][r] = 0.f;

    // ---- stage 1: g = sum over 3 segments x 28 k-tiles; no LDS, no barriers ----
#pragma unroll 1
    for (int seg = 0; seg < 3; ++seg) {
        const bf16x8* ap = Apk + (size_t)((bb * T_ + t + seg) * KSEG) * 256 + lane;
        const bf16x8* bp = Bpk + (size_t)((bx2 * 3 + seg) * KSEG) * 256 + lane;
#pragma unroll 2
        for (int kt = 0; kt < KSEG; ++kt) {
            bf16x8 av[4], bv[4];
#pragma unroll
            for (int i = 0; i < 4; ++i) av[i] = ap[i * 64];
#pragma unroll
            for (int i = 0; i < 4; ++i) bv[i] = bp[i * 64];
            ap += 256; bp += 256;
#pragma unroll
            for (int i = 0; i < 4; ++i)
#pragma unroll
                for (int j = 0; j < 4; ++j)
                    acc[i][j] = __builtin_amdgcn_mfma_f32_16x16x32_bf16(av[i], bv[j], acc[i][j], 0, 0, 0);
        }
    }

    // ---- transpose g (D-layout: c rows x m cols) -> Gw[m][c] bf16, per-wave LDS ----
    short* gw = &Gs[w * (64 * 72)];
#pragma unroll
    for (int af = 0; af < 4; ++af)
#pragma unroll
        for (int bf = 0; bf < 4; ++bf) {
            uint2 pk;
            pk.x = (unsigned)f2bf(acc[af][bf][0]) | ((unsigned)f2bf(acc[af][bf][1]) << 16);
            pk.y = (unsigned)f2bf(acc[af][bf][2]) | ((unsigned)f2bf(acc[af][bf][3]) << 16);
            *(uint2*)&gw[(16 * bf + lo) * 72 + 16 * af + 4 * q] = pk;   // c = 16af+4q+r, m = 16bf+lo
        }
    // same-wave RAW through LDS: compiler orders via lgkmcnt (verified round 2)

    // ---- stage 2 per m-group: z = g^T . W[gi], GLU, max over branches, store ----
#pragma unroll 1
    for (int mg = 0; mg < 4; ++mg) {
        const short* arow = &gw[(16 * mg + lo) * 72];
        const bf16x8 a2k0 = *(const bf16x8*)&arow[q * 8];        // c = 0..31
        const bf16x8 a2k1 = *(const bf16x8*)&arow[32 + q * 8];   // c = 32..63

        float om[4][4];
#pragma unroll
        for (int i = 0; i < 4; ++i)
#pragma unroll
            for (int r = 0; r < 4; ++r) om[i][r] = -3.4e38f;

#pragma unroll 1
        for (int gi = 0; gi < 3; ++gi) {
            f32x4 z[8];
#pragma unroll
            for (int i = 0; i < 8; ++i)
#pragma unroll
                for (int r = 0; r < 4; ++r) z[i][r] = 0.f;
#pragma unroll
            for (int df = 0; df < 8; ++df) {
                z[df] = __builtin_amdgcn_mfma_f32_16x16x32_bf16(
                    a2k0, Wpk[(size_t)(((gi * 8 + df) * 2 + 0)) * 64 + lane], z[df], 0, 0, 0);
                z[df] = __builtin_amdgcn_mfma_f32_16x16x32_bf16(
                    a2k1, Wpk[(size_t)(((gi * 8 + df) * 2 + 1)) * 64 + lane], z[df], 0, 0, 0);
            }
#pragma unroll
            for (int df = 0; df < 4; ++df) {
                const float b1 = bias[gi * 128 + 16 * df + lo];
                const float b2 = bias[gi * 128 + 64 + 16 * df + lo];
#pragma unroll
                for (int r = 0; r < 4; ++r) {
                    const float z1 = z[df][r] + b1;
                    const float z2 = z[df + 4][r] + b2;
                    const float sg = 1.0f / (1.0f + __expf(-z2));
                    om[df][r] = fmaxf(om[df][r], z1 * sg);
                }
            }
        }

        const int m16g = bx * 8 + mh * 4 + mg;      // 0..55
        const int mvb  = m16g * 16 + 4 * q;         // D row = 4q + r
#pragma unroll
        for (int df = 0; df < 4; ++df) {
            const int cout = 16 * df + lo;
            float* orow = out + ((size_t)(bb * C_ + cout) * TTW + t) * NV + mvb;
#pragma unroll
            for (int r = 0; r < 4; ++r) {
                if (mvb + r < NV) orow[r] = om[df][r];
            }
        }
    }
}

// ---------------- fallback: round-1 verified fp32 kernel (tiny ws) ----------------
__global__ __launch_bounds__(256) void stsgcl_fused(
    const float* __restrict__ x, const float* __restrict__ temb,
    const float* __restrict__ semb, const float* __restrict__ adj,
    const float* __restrict__ Wg, const float* __restrict__ bias,
    float* __restrict__ out)
{
    __shared__ union {
        struct { float As[32][64]; float Bs[32][64]; } s1;
        float Ws[64][128];
    } sm;
    __shared__ float Gsf[64][64];

    const int tid = threadIdx.x;
    const int bt = blockIdx.y;
    const int bb = bt / TTW;
    const int t  = bt % TTW;
    const int m0 = blockIdx.x * 64;
    const int tr = tid >> 4, tc = tid & 15;
    const int lrow = tid >> 2;
    const int kq = (tid & 3) * 8;

    const float* xrow = x + ((size_t)(bb * C_ + lrow) * T_ + t) * NV;
    const float* brow = adj + (size_t)(NV + m0 + lrow) * K3;
    const float* srow = semb + (size_t)lrow * NV;
    const float te0 = temb[lrow * T_ + t], te1 = temb[lrow * T_ + t + 1], te2 = temb[lrow * T_ + t + 2];

    float acc[4][4];
#pragma unroll
    for (int i = 0; i < 4; ++i)
#pragma unroll
        for (int j = 0; j < 4; ++j) acc[i][j] = 0.f;

    for (int kt = 0; kt < (K3 + 31) / 32; ++kt) {
        const int kg0 = kt * 32 + kq;
        {
            int tt, n;
            if (kg0 >= 2 * NV) { tt = 2; n = kg0 - 2 * NV; }
            else if (kg0 >= NV) { tt = 1; n = kg0 - NV; }
            else { tt = 0; n = kg0; }
#pragma unroll
            for (int i = 0; i < 8; ++i) {
                float v = 0.f;
                if (kg0 + i < K3) {
                    const float tev = (tt == 0) ? te0 : ((tt == 1) ? te1 : te2);
                    v = xrow[tt * NV + n] + tev + srow[n];
                }
                sm.s1.As[kq + i][lrow] = v;
                if (++n == NV) { n = 0; ++tt; }
            }
        }
#pragma unroll
        for (int i = 0; i < 8; ++i) sm.s1.Bs[kq + i][lrow] = brow[kg0 + i];
        __syncthreads();
#pragma unroll
        for (int kk = 0; kk < 32; ++kk) {
            const float4 a = *(const float4*)&sm.s1.As[kk][tr * 4];
            const float4 bv = *(const float4*)&sm.s1.Bs[kk][tc * 4];
            const float av[4] = {a.x, a.y, a.z, a.w};
            const float bw[4] = {bv.x, bv.y, bv.z, bv.w};
#pragma unroll
            for (int i = 0; i < 4; ++i)
#pragma unroll
                for (int j = 0; j < 4; ++j) acc[i][j] += av[i] * bw[j];
        }
        __syncthreads();
    }
#pragma unroll
    for (int i = 0; i < 4; ++i)
#pragma unroll
        for (int j = 0; j < 4; ++j) Gsf[tr * 4 + i][tc * 4 + j] = acc[i][j];

    const int pg = tid & 15, cg = tid >> 4;
    float omax[4][4];
#pragma unroll
    for (int i = 0; i < 4; ++i)
#pragma unroll
        for (int j = 0; j < 4; ++j) omax[i][j] = -3.4e38f;

    for (int gi = 0; gi < 3; ++gi) {
        __syncthreads();
        {
            const float4* wsrc = (const float4*)(Wg + (size_t)gi * C_ * 128);
            float4* wdst = (float4*)&sm.Ws[0][0];
#pragma unroll
            for (int i = 0; i < 8; ++i) wdst[tid + i * 256] = wsrc[tid + i * 256];
        }
        __syncthreads();
        float z1[4][4], z2[4][4];
#pragma unroll
        for (int j = 0; j < 4; ++j) {
            const float b1 = bias[gi * 128 + cg * 4 + j];
            const float b2 = bias[gi * 128 + 64 + cg * 4 + j];
#pragma unroll
            for (int i = 0; i < 4; ++i) { z1[i][j] = b1; z2[i][j] = b2; }
        }
#pragma unroll 8
        for (int cc = 0; cc < 64; ++cc) {
            const float4 gv = *(const float4*)&Gsf[cc][pg * 4];
            const float4 w1 = *(const float4*)&sm.Ws[cc][cg * 4];
            const float4 w2 = *(const float4*)&sm.Ws[cc][64 + cg * 4];
            const float gva[4] = {gv.x, gv.y, gv.z, gv.w};
            const float w1a[4] = {w1.x, w1.y, w1.z, w1.w};
            const float w2a[4] = {w2.x, w2.y, w2.z, w2.w};
#pragma unroll
            for (int i = 0; i < 4; ++i)
#pragma unroll
                for (int j = 0; j < 4; ++j) { z1[i][j] += gva[i] * w1a[j]; z2[i][j] += gva[i] * w2a[j]; }
        }
#pragma unroll
        for (int i = 0; i < 4; ++i)
#pragma unroll
            for (int j = 0; j < 4; ++j) {
                const float s = 1.0f / (1.0f + __expf(-z2[i][j]));
                omax[i][j] = fmaxf(omax[i][j], z1[i][j] * s);
            }
    }
    const int mmb = m0 + pg * 4;
#pragma unroll
    for (int j = 0; j < 4; ++j) {
        const int co = cg * 4 + j;
        float* orow = out + ((size_t)(bb * C_ + co) * TTW + t) * NV;
#pragma unroll
        for (int i = 0; i < 4; ++i) {
            const int mm = mmb + i;
            if (mm < NV) orow[mm] = omax[i][j];
        }
    }
}

extern "C" void kernel_launch(void* const* d_in, const int* in_sizes, int n_in,
                              void* d_out, int out_size, void* d_ws, size_t ws_size,
                              hipStream_t stream) {
    (void)in_sizes; (void)n_in; (void)out_size;
    const float* x    = (const float*)d_in[0];
    const float* temb = (const float*)d_in[1];
    const float* semb = (const float*)d_in[2];
    const float* adj  = (const float*)d_in[3];
    const float* Wg   = (const float*)d_in[4];
    const float* bias = (const float*)d_in[5];
    float* out = (float*)d_out;

    if (ws_size >= (size_t)WS_NEED) {
        bf16x8* Apk = (bf16x8*)((char*)d_ws + WS_A_OFF);
        u32x4*  Bpk = (u32x4*)((char*)d_ws + WS_B_OFF);
        u32x4*  Wpk = (u32x4*)((char*)d_ws + WS_W_OFF);

        prep_a<<<dim3(768), 256, 0, stream>>>(x, temb, semb, Apk);
        prep_b<<<dim3(1176), 256, 0, stream>>>(adj, Bpk);
        prep_w<<<dim3(12), 256, 0, stream>>>(Wg, Wpk);

        dim3 grid(7, 160);
        stsgcl_main<<<grid, 256, 0, stream>>>(Apk, (const bf16x8*)Bpk, (const bf16x8*)Wpk, bias, out);
    } else {
        dim3 grid(14, B_ * TTW);
        stsgcl_fused<<<grid, 256, 0, stream>>>(x, temb, semb, adj, Wg, bias, out);
    }
}